// Round 7
// baseline (405.082 us; speedup 1.0000x reference)
//
#include <hip/hip_runtime.h>
#include <hip/hip_bf16.h>

typedef __hip_bfloat16 bf16;
typedef __hip_bfloat162 bf162;

#define B_ 8
#define N_ 1024
#define M_ 1024
#define C_ 768
#define H_ 12
#define D_ 64

typedef __attribute__((ext_vector_type(8))) short short8v;
typedef __attribute__((ext_vector_type(4))) float f32x4;

__device__ __forceinline__ float bf2f(bf16 v){ return __bfloat162float(v); }
__device__ __forceinline__ bf16 f2bf(float v){ return __float2bfloat16(v); }

__device__ __forceinline__ void gl_lds16(const bf16* g, bf16* l){
  __builtin_amdgcn_global_load_lds((const __attribute__((address_space(1))) unsigned*)g,
                                   (__attribute__((address_space(3))) unsigned*)l, 16, 0, 0);
}

// ---------------- prep: fp32 -> bf16 convert (8 elems/thread) ----------------
__global__ __launch_bounds__(256)
void cvt_bf16(const float* __restrict__ in, bf16* __restrict__ out, int n8){
  int i = blockIdx.x*256 + threadIdx.x;
  if (i < n8){
    const float4* ip = reinterpret_cast<const float4*>(in) + 2*(size_t)i;
    float4 a = ip[0], b = ip[1];
    union { uint4 u; bf16 h[8]; } pk;
    pk.h[0]=f2bf(a.x); pk.h[1]=f2bf(a.y); pk.h[2]=f2bf(a.z); pk.h[3]=f2bf(a.w);
    pk.h[4]=f2bf(b.x); pk.h[5]=f2bf(b.y); pk.h[6]=f2bf(b.z); pk.h[7]=f2bf(b.w);
    reinterpret_cast<uint4*>(out)[i] = pk.u;
  }
}

// ---------------- prep: W[K][N] f32 -> Wt[N][K] bf16 ----------------
__global__ __launch_bounds__(256)
void transpose_w(const float* __restrict__ W, bf16* __restrict__ Wt, int K, int N){
  __shared__ float tile[32][33];
  const int n0 = blockIdx.x*32, k0 = blockIdx.y*32;
  const int tx = threadIdx.x & 31, ty = threadIdx.x >> 5;
#pragma unroll
  for (int i=0;i<32;i+=8) tile[ty+i][tx] = W[(size_t)(k0+ty+i)*N + n0+tx];
  __syncthreads();
#pragma unroll
  for (int i=0;i<32;i+=8) Wt[(size_t)(n0+ty+i)*K + k0+tx] = f2bf(tile[tx][ty+i]);
}

// ---- prep: per-(b,h) panel. Y_i tiled (m>>5)*2048 + d*32 + (m&31). Y2 in place over Vt. Also SV.
__global__ __launch_bounds__(1024)
void yprep(bf16* __restrict__ Vt, bf16* __restrict__ Y0, bf16* __restrict__ Y1,
           float* __restrict__ SV, const float* __restrict__ conv_w)
{
  __shared__ bf16 sm[65536];
  const int t = threadIdx.x;
  const int bh = blockIdx.x;
  const int h = bh % H_;
  const size_t pbase = (size_t)bh * 65536;

  float w[9];
#pragma unroll
  for (int q=0;q<9;q++) w[q] = conv_w[h*9+q];

#pragma unroll
  for (int k=0;k<8;k++){
    int idx = k*8192 + t*8;
    *reinterpret_cast<uint4*>(&sm[idx]) = *reinterpret_cast<const uint4*>(Vt + pbase + idx);
  }
  __syncthreads();

  const int d = t >> 4;
  const int j = t & 15;
  float ssum = 0.f;
#pragma unroll
  for (int k=0;k<8;k++){
    const int moff = j*64 + k*8;
    const int base = d*1024 + moff;
    union { uint4 u; bf16 hh[8]; } mv;
    mv.u = *reinterpret_cast<const uint4*>(&sm[base]);
    float v[8];
#pragma unroll
    for (int e=0;e<8;e++) v[e] = bf2f(mv.hh[e]);
    float vl = (moff == 0)    ? 0.f : bf2f(sm[base-1]);
    float vr = (moff == 1016) ? 0.f : bf2f(sm[base+8]);

    union { uint4 u; bf16 hh[8]; } o0, o1, o2;
#pragma unroll
    for (int m=0;m<8;m++){
      float vm1 = (m==0) ? vl : v[m-1];
      float vp1 = (m==7) ? vr : v[m+1];
      o0.hh[m] = f2bf(w[0]*vp1 + w[1]*v[m] + w[2]*vm1);
      o1.hh[m] = f2bf(w[3]*vp1 + w[4]*v[m] + w[5]*vm1);
      o2.hh[m] = f2bf(w[6]*vp1 + w[7]*v[m] + w[8]*vm1);
      ssum += v[m];
    }
    size_t go = pbase + ((size_t)(moff>>5)<<11) + d*32 + (moff&31);
    *reinterpret_cast<uint4*>(Y0 + go) = o0.u;
    *reinterpret_cast<uint4*>(Y1 + go) = o1.u;
    *reinterpret_cast<uint4*>(Vt + go) = o2.u;
  }

  ssum += __shfl_xor(ssum, 1);
  ssum += __shfl_xor(ssum, 2);
  ssum += __shfl_xor(ssum, 4);
  ssum += __shfl_xor(ssum, 8);
  if (j == 0) SV[bh*64 + d] = ssum;
}

// ---------------- bf16 MFMA GEMM: A[8192][K] @ Bt[N][K]^T ----------------
__global__ __launch_bounds__(256)
void gemm_bf16(const bf16* __restrict__ A, const bf16* __restrict__ Bt, int K,
               int nbx, const float* __restrict__ bias,
               float* __restrict__ outf, bf16* __restrict__ outQ,
               bf16* __restrict__ outK, bf16* __restrict__ outV, int mode)
{
  __shared__ bf16 As[128*32];
  __shared__ bf16 Bs[128*32];

  const int nwg = 64*nbx, cpx = nwg >> 3;
  int bid = blockIdx.x;
  bid = (bid & 7)*cpx + (bid >> 3);
  const int rowb = bid / nbx, colb = bid - rowb*nbx;
  const int row0 = rowb*128, c0 = colb*128;

  const int t = threadIdx.x;
  const int w = t>>6, l = t&63, lr = l&15, g = l>>4;
  const int wr = w>>1, wc = w&1;

  const bf16* Ap = A + (size_t)row0*K;
  const bf16* Bp = Bt + (size_t)c0*K;
  const int srow = t>>2;
  const int schunk = (t&3)*8;

  f32x4 acc[4][4];
#pragma unroll
  for (int mi=0;mi<4;mi++)
#pragma unroll
    for (int ni=0;ni<4;ni++) acc[mi][ni] = (f32x4){0.f,0.f,0.f,0.f};

  for (int k0 = 0; k0 < K; k0 += 32){
    gl_lds16(Ap + (size_t)srow*K      + k0 + schunk, As + t*8);
    gl_lds16(Ap + (size_t)(srow+64)*K + k0 + schunk, As + 2048 + t*8);
    gl_lds16(Bp + (size_t)srow*K      + k0 + schunk, Bs + t*8);
    gl_lds16(Bp + (size_t)(srow+64)*K + k0 + schunk, Bs + 2048 + t*8);
    __syncthreads();

    short8v a[4], b[4];
#pragma unroll
    for (int mi=0;mi<4;mi++)
      a[mi] = *reinterpret_cast<const short8v*>(&As[(wr*64+mi*16+lr)*32 + g*8]);
#pragma unroll
    for (int ni=0;ni<4;ni++)
      b[ni] = *reinterpret_cast<const short8v*>(&Bs[(wc*64+ni*16+lr)*32 + g*8]);
#pragma unroll
    for (int mi=0;mi<4;mi++)
#pragma unroll
      for (int ni=0;ni<4;ni++)
        acc[mi][ni] = __builtin_amdgcn_mfma_f32_16x16x32_bf16(a[mi], b[ni], acc[mi][ni], 0,0,0);
    __syncthreads();
  }

  if (mode == 2){
    float bv[4];
#pragma unroll
    for (int ni=0;ni<4;ni++) bv[ni] = bias[c0 + wc*64 + ni*16 + lr];
#pragma unroll
    for (int mi=0;mi<4;mi++)
#pragma unroll
      for (int ni=0;ni<4;ni++){
        int c = c0 + wc*64 + ni*16 + lr;
#pragma unroll
        for (int q=0;q<4;q++){
          int grow = row0 + wr*64 + mi*16 + g*4 + q;
          outf[(size_t)grow*C_ + c] = acc[mi][ni][q] + bv[ni];
        }
      }
  } else if (mode == 0){
#pragma unroll
    for (int mi=0;mi<4;mi++)
#pragma unroll
      for (int ni=0;ni<4;ni++){
        int c = c0 + wc*64 + ni*16 + lr;
        int h = c >> 6, dd = c & 63;
#pragma unroll
        for (int q=0;q<4;q++){
          int grow = row0 + wr*64 + mi*16 + g*4 + q;
          int b = grow >> 10, n = grow & 1023;
          outQ[((((size_t)b*H_ + h)*N_ + n)<<6) + dd] = f2bf(acc[mi][ni][q]);
        }
      }
  } else {
#pragma unroll
    for (int mi=0;mi<4;mi++)
#pragma unroll
      for (int ni=0;ni<4;ni++){
        int c = c0 + wc*64 + ni*16 + lr;
        if (c < 768){
          int h = c >> 6, dd = c & 63;
#pragma unroll
          for (int q=0;q<4;q++){
            int grow = row0 + wr*64 + mi*16 + g*4 + q;
            int b = grow >> 10, m = grow & 1023;
            int eidx = ((m>>4)<<10) + ((dd>>3)<<7) + ((m&15)<<3) + (dd&7);
            outK[((size_t)b*H_ + h)*65536 + eidx] = f2bf(acc[mi][ni][q]);
          }
        } else {
          int cc = c - 768;
          int h = cc >> 6, dd = cc & 63;
          int grow = row0 + wr*64 + mi*16 + g*4;
          int b = grow >> 10, m = grow & 1023;
          union { ushort4 u; bf16 hh[4]; } pk;
#pragma unroll
          for (int q=0;q<4;q++) pk.hh[q] = f2bf(acc[mi][ni][q]);
          size_t off = (((size_t)b*H_ + h)*D_ + dd)*(size_t)M_ + m;
          *reinterpret_cast<ushort4*>(&outV[off]) = pk.u;
        }
      }
  }
}

// -------- flash attention: swapped QK^T, online softmax, 3x PV, in-reg n-shift combine
__global__ __launch_bounds__(512, 4)
void attn_flash(const bf16* __restrict__ Qb, const bf16* __restrict__ Kb,
                const bf16* __restrict__ Y0, const bf16* __restrict__ Y1,
                const bf16* __restrict__ Y2, const float* __restrict__ SV,
                const float* __restrict__ conv_b, bf16* __restrict__ midb,
                float* __restrict__ E0, float* __restrict__ E127,
                float* __restrict__ X0, float* __restrict__ X1)
{
  __shared__ bf16  pbuf[8][2048];   // per-wave P^T chunk [16 rows][128 m], swizzled (32 KB)
  __shared__ float eU0[8][64];      // wave w's U0 row15
  __shared__ float eU2[8][64];      // wave w's U2 row0

  const int t = threadIdx.x, w = t>>6, l = t&63, lr = l&15, g = l>>4;
  // XCD-chunked map: 768 WGs -> 8 XCD slices of 96 (12 panels x 8 tiles, tiles adjacent)
  int bid2 = (blockIdx.x & 7)*96 + (blockIdx.x >> 3);
  const int bh = bid2 >> 3, tile = bid2 & 7;
  const int b = bh / H_, h = bh - b*H_;
  const int n0 = tile*128;

  const bf16* Qp = Qb + (size_t)bh*65536;
  const bf16* Kp = Kb + (size_t)bh*65536;
  const size_t yb = (size_t)bh*65536;
  const float cbv = conv_b[h];
  const float scale = 0.125f;

  // Q B-frags for q-row (lr) of this wave: n = n0 + w*16 + lr
  const bf16* qp = Qp + (size_t)(n0 + w*16 + lr)*D_ + g*8;
  short8v qf0 = *reinterpret_cast<const short8v*>(qp);
  short8v qf1 = *reinterpret_cast<const short8v*>(qp + 32);

  float mrun = -INFINITY, lsum = 0.f;
  f32x4 U[3][4];
#pragma unroll
  for (int y=0;y<3;y++)
#pragma unroll
    for (int dt=0;dt<4;dt++) U[y][dt] = (f32x4){0.f,0.f,0.f,0.f};

  bf16* pw = pbuf[w];
  const int wswz = (lr & 7) << 3;

  for (int mc = 0; mc < 8; ++mc){
    // ---- QK swapped: s[st] = S^T rows m = st*16+g*4+q, col(qrow) = lr ----
    f32x4 s[8];
    const bf16* kc = Kp + mc*8192 + g*128 + lr*8;
#pragma unroll
    for (int st=0; st<8; ++st){
      short8v k0 = *reinterpret_cast<const short8v*>(kc + st*1024);
      short8v k1 = *reinterpret_cast<const short8v*>(kc + st*1024 + 512);
      f32x4 a = (f32x4){0.f,0.f,0.f,0.f};
      a = __builtin_amdgcn_mfma_f32_16x16x32_bf16(k0, qf0, a, 0,0,0);
      a = __builtin_amdgcn_mfma_f32_16x16x32_bf16(k1, qf1, a, 0,0,0);
      s[st] = a;
    }
    // ---- online softmax (per q-row lr) ----
    float cmax = -1e30f;
#pragma unroll
    for (int st=0; st<8; ++st)
#pragma unroll
      for (int q=0;q<4;q++) cmax = fmaxf(cmax, s[st][q]);
    cmax = fmaxf(cmax, __shfl_xor(cmax, 16));
    cmax = fmaxf(cmax, __shfl_xor(cmax, 32));
    float mnew = fmaxf(mrun, cmax);
    float alpha = __expf((mrun - mnew)*scale);
    mrun = mnew;

    float psum = 0.f;
#pragma unroll
    for (int st=0; st<8; ++st){
      union { ushort4 u; bf16 hh[4]; } pk;
#pragma unroll
      for (int q=0;q<4;q++){
        float p = __expf((s[st][q] - mrun)*scale);
        psum += p;
        pk.hh[q] = f2bf(p);
      }
      int col = (st*16 + g*4) ^ wswz;
      *reinterpret_cast<ushort4*>(pw + lr*128 + col) = pk.u;
    }
    lsum = lsum*alpha + psum;

    // rescale U by row-alpha (U row = g*4+q; alpha lives at lane lr=row)
    float ar[4];
#pragma unroll
    for (int q=0;q<4;q++) ar[q] = __shfl(alpha, g*4+q);
#pragma unroll
    for (int y=0;y<3;y++)
#pragma unroll
      for (int dt=0;dt<4;dt++)
#pragma unroll
        for (int q=0;q<4;q++) U[y][dt][q] *= ar[q];

    // ---- PV: U += P_chunk @ Y_chunk (per-wave LDS, no barrier) ----
#pragma unroll
    for (int ks=0; ks<4; ++ks){
      short8v a = *reinterpret_cast<const short8v*>(pw + lr*128 + ((ks*32 + g*8) ^ wswz));
      const size_t eb = yb + (size_t)((mc*4+ks)<<11) + lr*32 + g*8;
#pragma unroll
      for (int dt=0; dt<4; ++dt){
        const size_t eo = eb + dt*512;
        U[0][dt] = __builtin_amdgcn_mfma_f32_16x16x32_bf16(a, *reinterpret_cast<const short8v*>(Y0+eo), U[0][dt], 0,0,0);
        U[1][dt] = __builtin_amdgcn_mfma_f32_16x16x32_bf16(a, *reinterpret_cast<const short8v*>(Y1+eo), U[1][dt], 0,0,0);
        U[2][dt] = __builtin_amdgcn_mfma_f32_16x16x32_bf16(a, *reinterpret_cast<const short8v*>(Y2+eo), U[2][dt], 0,0,0);
      }
    }
  }

  // ---- finalize: divide by row-sum ----
  lsum += __shfl_xor(lsum, 16);
  lsum += __shfl_xor(lsum, 32);
  float linv = 1.f/lsum;
  float lq[4];
#pragma unroll
  for (int q=0;q<4;q++) lq[q] = __shfl(linv, g*4+q);
#pragma unroll
  for (int y=0;y<3;y++)
#pragma unroll
    for (int dt=0;dt<4;dt++)
#pragma unroll
      for (int q=0;q<4;q++) U[y][dt][q] *= lq[q];

  float sv[4];
#pragma unroll
  for (int dt=0;dt<4;dt++) sv[dt] = SV[bh*64 + dt*16 + lr];

  // stage wave-edge rows
  if (g == 3){
#pragma unroll
    for (int dt=0;dt<4;dt++) eU0[w][dt*16+lr] = U[0][dt][3];
  }
  if (g == 0){
#pragma unroll
    for (int dt=0;dt<4;dt++) eU2[w][dt*16+lr] = U[2][dt][0];
  }
  __syncthreads();

  // ---- combine O[r] = U0[r-1] + U1[r] + U2[r+1] + cb*SV, write mid (skip tile-edge rows) ----
#pragma unroll
  for (int dt=0; dt<4; ++dt){
    float u0s = __shfl(U[0][dt][3], (l - 16) & 63);
    if (g == 0) u0s = (w > 0) ? eU0[w-1][dt*16+lr] : 0.f;
    float u2s = __shfl(U[2][dt][0], (l + 16) & 63);
    if (g == 3) u2s = (w < 7) ? eU2[w+1][dt*16+lr] : 0.f;

    float base = cbv*sv[dt];
    float o[4];
    o[0] = u0s         + U[1][dt][0] + U[2][dt][1] + base;
    o[1] = U[0][dt][0] + U[1][dt][1] + U[2][dt][2] + base;
    o[2] = U[0][dt][1] + U[1][dt][2] + U[2][dt][3] + base;
    o[3] = U[0][dt][2] + U[1][dt][3] + u2s         + base;

    const int d = dt*16 + lr;
#pragma unroll
    for (int q=0;q<4;q++){
      int r = w*16 + g*4 + q;
      if (r != 0 && r != 127){
        int n = n0 + r;
        midb[((size_t)b*N_ + n)*C_ + h*D_ + d] = f2bf(o[q]);
      }
    }

    // tile-edge partials + cross terms
    const int ei = (bh*8 + tile)*64 + d;
    if (w == 0 && g == 0){
      E0[ei] = U[1][dt][0] + U[2][dt][1] + base;
      X1[ei] = U[2][dt][0];
    }
    if (w == 7 && g == 3){
      E127[ei] = U[0][dt][2] + U[1][dt][3] + base;
      X0[ei]   = U[0][dt][3];
    }
  }
}

// ---- patch tile-edge rows: O[n0] = E0 + X0[prev], O[n0+127] = E127 + X1[next] ----
__global__ __launch_bounds__(256)
void edge_patch(const float* __restrict__ E0, const float* __restrict__ E127,
                const float* __restrict__ X0, const float* __restrict__ X1,
                bf16* __restrict__ midb)
{
  int idx = blockIdx.x*256 + threadIdx.x;   // 98304 total
  int d = idx & 63;
  int rs = (idx >> 6) & 1;
  int tile = (idx >> 7) & 7;
  int bh = idx >> 10;
  int b = bh / H_, h = bh - b*H_;
  int n0 = tile*128;
  float v; int n;
  if (rs == 0){
    v = E0[(bh*8+tile)*64 + d] + (tile > 0 ? X0[(bh*8+tile-1)*64 + d] : 0.f);
    n = n0;
  } else {
    v = E127[(bh*8+tile)*64 + d] + (tile < 7 ? X1[(bh*8+tile+1)*64 + d] : 0.f);
    n = n0 + 127;
  }
  midb[((size_t)b*N_ + n)*C_ + h*D_ + d] = f2bf(v);
}

extern "C" void kernel_launch(void* const* d_in, const int* in_sizes, int n_in,
                              void* d_out, int out_size, void* d_ws, size_t ws_size,
                              hipStream_t stream) {
  const float* x     = (const float*)d_in[0];
  const float* ctx   = (const float*)d_in[1];
  const float* Wq    = (const float*)d_in[2];
  const float* Wkv   = (const float*)d_in[3];
  const float* convw = (const float*)d_in[4];
  const float* convb = (const float*)d_in[5];
  const float* Wp    = (const float*)d_in[6];
  const float* bp    = (const float*)d_in[7];
  float* out = (float*)d_out;

  char* ws = (char*)d_ws;
  bf16* buf0 = (bf16*)(ws);                  // 12582912 (xb -> ctxb -> mid)
  bf16* Wqt  = (bf16*)(ws + 12582912);       // 1179648
  bf16* Wkvt = (bf16*)(ws + 13762560);       // 2359296
  bf16* Wpt  = (bf16*)(ws + 16121856);       // 1179648
  bf16* Qb   = (bf16*)(ws + 17301504);       // 12582912
  bf16* Kb   = (bf16*)(ws + 29884416);       // 12582912 (frag-tiled)
  bf16* Vt   = (bf16*)(ws + 42467328);       // 12582912 (V row-major -> Y2 tiled)
  float* SVb = (float*)(ws + 55050240);      // 24576
  float* E0  = (float*)(ws + 55074816);      // 196608
  float* E127= (float*)(ws + 55271424);      // 196608
  float* X0  = (float*)(ws + 55468032);      // 196608
  float* X1  = (float*)(ws + 55664640);      // 196608 -> end 55861248

  // Y0/Y1 scratch in d_out (25.2 MB), fully overwritten by final GEMM
  bf16* Y0 = (bf16*)d_out;
  bf16* Y1 = (bf16*)((char*)d_out + 12582912);

  transpose_w<<<dim3(24,24), 256, 0, stream>>>(Wq,  Wqt,  768, 768);
  transpose_w<<<dim3(48,24), 256, 0, stream>>>(Wkv, Wkvt, 768, 1536);
  transpose_w<<<dim3(24,24), 256, 0, stream>>>(Wp,  Wpt,  768, 768);

  cvt_bf16<<<3072, 256, 0, stream>>>(x, buf0, 786432);
  gemm_bf16<<<384, 256, 0, stream>>>(buf0, Wqt, 768, 6, nullptr, nullptr, Qb, nullptr, nullptr, 0);
  cvt_bf16<<<3072, 256, 0, stream>>>(ctx, buf0, 786432);
  gemm_bf16<<<768, 256, 0, stream>>>(buf0, Wkvt, 768, 12, nullptr, nullptr, nullptr, Kb, Vt, 1);

  yprep<<<96, 1024, 0, stream>>>(Vt, Y0, Y1, SVb, convw);

  attn_flash<<<768, 512, 0, stream>>>(Qb, Kb, Y0, Y1, Vt, SVb, convb, buf0,
                                      E0, E127, X0, X1);
  edge_patch<<<384, 256, 0, stream>>>(E0, E127, X0, X1, buf0);

  gemm_bf16<<<384, 256, 0, stream>>>(buf0, Wpt, 768, 6, bp, out, nullptr, nullptr, nullptr, 2);
}

// Round 8
// 219.507 us; speedup vs baseline: 1.8454x; 1.8454x over previous
//
#include <hip/hip_runtime.h>
#include <hip/hip_bf16.h>

typedef __hip_bfloat16 bf16;
typedef __hip_bfloat162 bf162;

#define B_ 8
#define N_ 1024
#define M_ 1024
#define C_ 768
#define H_ 12
#define D_ 64

typedef __attribute__((ext_vector_type(8))) short short8v;
typedef __attribute__((ext_vector_type(4))) float f32x4;

__device__ __forceinline__ float bf2f(bf16 v){ return __bfloat162float(v); }
__device__ __forceinline__ bf16 f2bf(float v){ return __float2bfloat16(v); }

__device__ __forceinline__ void gl_lds16(const bf16* g, bf16* l){
  __builtin_amdgcn_global_load_lds((const __attribute__((address_space(1))) unsigned*)g,
                                   (__attribute__((address_space(3))) unsigned*)l, 16, 0, 0);
}

// ---------------- prep: fp32 -> bf16 convert (8 elems/thread) ----------------
__global__ __launch_bounds__(256)
void cvt_bf16(const float* __restrict__ in, bf16* __restrict__ out, int n8){
  int i = blockIdx.x*256 + threadIdx.x;
  if (i < n8){
    const float4* ip = reinterpret_cast<const float4*>(in) + 2*(size_t)i;
    float4 a = ip[0], b = ip[1];
    union { uint4 u; bf16 h[8]; } pk;
    pk.h[0]=f2bf(a.x); pk.h[1]=f2bf(a.y); pk.h[2]=f2bf(a.z); pk.h[3]=f2bf(a.w);
    pk.h[4]=f2bf(b.x); pk.h[5]=f2bf(b.y); pk.h[6]=f2bf(b.z); pk.h[7]=f2bf(b.w);
    reinterpret_cast<uint4*>(out)[i] = pk.u;
  }
}

// ---------------- prep: W[K][N] f32 -> Wt[N][K] bf16 ----------------
__global__ __launch_bounds__(256)
void transpose_w(const float* __restrict__ W, bf16* __restrict__ Wt, int K, int N){
  __shared__ float tile[32][33];
  const int n0 = blockIdx.x*32, k0 = blockIdx.y*32;
  const int tx = threadIdx.x & 31, ty = threadIdx.x >> 5;
#pragma unroll
  for (int i=0;i<32;i+=8) tile[ty+i][tx] = W[(size_t)(k0+ty+i)*N + n0+tx];
  __syncthreads();
#pragma unroll
  for (int i=0;i<32;i+=8) Wt[(size_t)(n0+ty+i)*K + k0+tx] = f2bf(tile[tx][ty+i]);
}

// ---- prep: per-(b,h) panel. Y_i tiled (m>>5)*2048 + d*32 + swizzled-m5.
// m-block index (m5>>3) is XORed with ((d>>1)&3) so the attn kernel's LDS
// ds_read_b128 of Y frags is 2-way bank-conflict-free (rule: both-sides swizzle).
// Y2 in place over Vt. Also SV row sums.
__global__ __launch_bounds__(1024)
void yprep(bf16* __restrict__ Vt, bf16* __restrict__ Y0, bf16* __restrict__ Y1,
           float* __restrict__ SV, const float* __restrict__ conv_w)
{
  __shared__ bf16 sm[65536];
  const int t = threadIdx.x;
  const int bh = blockIdx.x;
  const int h = bh % H_;
  const size_t pbase = (size_t)bh * 65536;

  float w[9];
#pragma unroll
  for (int q=0;q<9;q++) w[q] = conv_w[h*9+q];

#pragma unroll
  for (int k=0;k<8;k++){
    int idx = k*8192 + t*8;
    *reinterpret_cast<uint4*>(&sm[idx]) = *reinterpret_cast<const uint4*>(Vt + pbase + idx);
  }
  __syncthreads();

  const int d = t >> 4;
  const int j = t & 15;
  const int xb = (d >> 1) & 3;
  float ssum = 0.f;
#pragma unroll
  for (int k=0;k<8;k++){
    const int moff = j*64 + k*8;
    const int base = d*1024 + moff;
    union { uint4 u; bf16 hh[8]; } mv;
    mv.u = *reinterpret_cast<const uint4*>(&sm[base]);
    float v[8];
#pragma unroll
    for (int e=0;e<8;e++) v[e] = bf2f(mv.hh[e]);
    float vl = (moff == 0)    ? 0.f : bf2f(sm[base-1]);
    float vr = (moff == 1016) ? 0.f : bf2f(sm[base+8]);

    union { uint4 u; bf16 hh[8]; } o0, o1, o2;
#pragma unroll
    for (int m=0;m<8;m++){
      float vm1 = (m==0) ? vl : v[m-1];
      float vp1 = (m==7) ? vr : v[m+1];
      o0.hh[m] = f2bf(w[0]*vp1 + w[1]*v[m] + w[2]*vm1);
      o1.hh[m] = f2bf(w[3]*vp1 + w[4]*v[m] + w[5]*vm1);
      o2.hh[m] = f2bf(w[6]*vp1 + w[7]*v[m] + w[8]*vm1);
      ssum += v[m];
    }
    const int blk = (moff >> 3) & 3;                  // m5>>3
    size_t go = pbase + ((size_t)(moff>>5)<<11) + d*32 + ((blk ^ xb)<<3);
    *reinterpret_cast<uint4*>(Y0 + go) = o0.u;
    *reinterpret_cast<uint4*>(Y1 + go) = o1.u;
    *reinterpret_cast<uint4*>(Vt + go) = o2.u;
  }

  ssum += __shfl_xor(ssum, 1);
  ssum += __shfl_xor(ssum, 2);
  ssum += __shfl_xor(ssum, 4);
  ssum += __shfl_xor(ssum, 8);
  if (j == 0) SV[bh*64 + d] = ssum;
}

// ---------------- bf16 MFMA GEMM: A[8192][K] @ Bt[N][K]^T ----------------
// mode 0: out -> Qb[b,h,n,d] bf16, PRE-SCALED by 0.125 (softmax scale folded)
// mode 1: cols<768 -> Kb tiled frag-major; cols>=768 -> Vt[b,h,d,m]
// mode 2: +bias -> outf fp32
__global__ __launch_bounds__(256)
void gemm_bf16(const bf16* __restrict__ A, const bf16* __restrict__ Bt, int K,
               int nbx, const float* __restrict__ bias,
               float* __restrict__ outf, bf16* __restrict__ outQ,
               bf16* __restrict__ outK, bf16* __restrict__ outV, int mode)
{
  __shared__ bf16 As[128*32];
  __shared__ bf16 Bs[128*32];

  const int nwg = 64*nbx, cpx = nwg >> 3;
  int bid = blockIdx.x;
  bid = (bid & 7)*cpx + (bid >> 3);
  const int rowb = bid / nbx, colb = bid - rowb*nbx;
  const int row0 = rowb*128, c0 = colb*128;

  const int t = threadIdx.x;
  const int w = t>>6, l = t&63, lr = l&15, g = l>>4;
  const int wr = w>>1, wc = w&1;

  const bf16* Ap = A + (size_t)row0*K;
  const bf16* Bp = Bt + (size_t)c0*K;
  const int srow = t>>2;
  const int schunk = (t&3)*8;

  f32x4 acc[4][4];
#pragma unroll
  for (int mi=0;mi<4;mi++)
#pragma unroll
    for (int ni=0;ni<4;ni++) acc[mi][ni] = (f32x4){0.f,0.f,0.f,0.f};

  for (int k0 = 0; k0 < K; k0 += 32){
    gl_lds16(Ap + (size_t)srow*K      + k0 + schunk, As + t*8);
    gl_lds16(Ap + (size_t)(srow+64)*K + k0 + schunk, As + 2048 + t*8);
    gl_lds16(Bp + (size_t)srow*K      + k0 + schunk, Bs + t*8);
    gl_lds16(Bp + (size_t)(srow+64)*K + k0 + schunk, Bs + 2048 + t*8);
    __syncthreads();

    short8v a[4], b[4];
#pragma unroll
    for (int mi=0;mi<4;mi++)
      a[mi] = *reinterpret_cast<const short8v*>(&As[(wr*64+mi*16+lr)*32 + g*8]);
#pragma unroll
    for (int ni=0;ni<4;ni++)
      b[ni] = *reinterpret_cast<const short8v*>(&Bs[(wc*64+ni*16+lr)*32 + g*8]);
#pragma unroll
    for (int mi=0;mi<4;mi++)
#pragma unroll
      for (int ni=0;ni<4;ni++)
        acc[mi][ni] = __builtin_amdgcn_mfma_f32_16x16x32_bf16(a[mi], b[ni], acc[mi][ni], 0,0,0);
    __syncthreads();
  }

  if (mode == 2){
    float bv[4];
#pragma unroll
    for (int ni=0;ni<4;ni++) bv[ni] = bias[c0 + wc*64 + ni*16 + lr];
#pragma unroll
    for (int mi=0;mi<4;mi++)
#pragma unroll
      for (int ni=0;ni<4;ni++){
        int c = c0 + wc*64 + ni*16 + lr;
#pragma unroll
        for (int q=0;q<4;q++){
          int grow = row0 + wr*64 + mi*16 + g*4 + q;
          outf[(size_t)grow*C_ + c] = acc[mi][ni][q] + bv[ni];
        }
      }
  } else if (mode == 0){
#pragma unroll
    for (int mi=0;mi<4;mi++)
#pragma unroll
      for (int ni=0;ni<4;ni++){
        int c = c0 + wc*64 + ni*16 + lr;
        int h = c >> 6, dd = c & 63;
#pragma unroll
        for (int q=0;q<4;q++){
          int grow = row0 + wr*64 + mi*16 + g*4 + q;
          int b = grow >> 10, n = grow & 1023;
          outQ[((((size_t)b*H_ + h)*N_ + n)<<6) + dd] = f2bf(acc[mi][ni][q] * 0.125f);
        }
      }
  } else {
#pragma unroll
    for (int mi=0;mi<4;mi++)
#pragma unroll
      for (int ni=0;ni<4;ni++){
        int c = c0 + wc*64 + ni*16 + lr;
        if (c < 768){
          int h = c >> 6, dd = c & 63;
#pragma unroll
          for (int q=0;q<4;q++){
            int grow = row0 + wr*64 + mi*16 + g*4 + q;
            int b = grow >> 10, m = grow & 1023;
            int eidx = ((m>>4)<<10) + ((dd>>3)<<7) + ((m&15)<<3) + (dd&7);
            outK[((size_t)b*H_ + h)*65536 + eidx] = f2bf(acc[mi][ni][q]);
          }
        } else {
          int cc = c - 768;
          int h = cc >> 6, dd = cc & 63;
          int grow = row0 + wr*64 + mi*16 + g*4;
          int b = grow >> 10, m = grow & 1023;
          union { ushort4 u; bf16 hh[4]; } pk;
#pragma unroll
          for (int q=0;q<4;q++) pk.hh[q] = f2bf(acc[mi][ni][q]);
          size_t off = (((size_t)b*H_ + h)*D_ + dd)*(size_t)M_ + m;
          *reinterpret_cast<ushort4*>(&outV[off]) = pk.u;
        }
      }
  }
}

// -------- cooperative flash attention: LDS-staged K/Y chunks, online softmax,
// per-wave P buffer, 3x PV, in-reg n-shift combine, coalesced output.
__global__ __launch_bounds__(512, 4)
void attn_coop(const bf16* __restrict__ Qb, const bf16* __restrict__ Kb,
               const bf16* __restrict__ Y0, const bf16* __restrict__ Y1,
               const bf16* __restrict__ Y2, const float* __restrict__ SV,
               const float* __restrict__ conv_b, bf16* __restrict__ midb,
               float* __restrict__ E0, float* __restrict__ E127,
               float* __restrict__ X0, float* __restrict__ X1)
{
  __shared__ bf16  sS[16384];       // 32 KB: [0:4K)=K, [4K:8K)=Y0, [8K:12K)=Y1, [12K:16K)=Y2
  __shared__ bf16  pbuf[8][1024];   // 16 KB per-wave P [16 q][64 m]; reused as smOut
  __shared__ float eU0[8][64];
  __shared__ float eU2[8][64];

  const int t = threadIdx.x, w = t>>6, l = t&63, lr = l&15, g = l>>4;
  // XCD-chunked map: 768 WGs -> 8 slices of 96 (12 panels x 8 adjacent tiles)
  int bid2 = (blockIdx.x & 7)*96 + (blockIdx.x >> 3);
  const int bh = bid2 >> 3, tile = bid2 & 7;
  const int b = bh / H_, h = bh - b*H_;
  const int n0 = tile*128;

  const bf16* Qp  = Qb + (size_t)bh*65536;
  const bf16* Kp  = Kb + (size_t)bh*65536;
  const bf16* Y0p = Y0 + (size_t)bh*65536;
  const bf16* Y1p = Y1 + (size_t)bh*65536;
  const bf16* Y2p = Y2 + (size_t)bh*65536;
  const float cbv = conv_b[h];

  // Q B-frags (scale pre-folded into Q), q-row n = n0 + w*16 + lr
  const bf16* qp = Qp + (size_t)(n0 + w*16 + lr)*D_ + g*8;
  short8v qf0 = *reinterpret_cast<const short8v*>(qp);
  short8v qf1 = *reinterpret_cast<const short8v*>(qp + 32);

  float mrun = -INFINITY, lsum = 0.f;
  f32x4 U[3][4];
#pragma unroll
  for (int y=0;y<3;y++)
#pragma unroll
    for (int dt=0;dt<4;dt++) U[y][dt] = (f32x4){0.f,0.f,0.f,0.f};

  bf16* pw = pbuf[w];
  const int pswz = (lr & 7) << 3;
  const int yswz = (lr >> 1) & 3;     // Y m-block XOR key (matches yprep)

  for (int mc = 0; mc < 16; ++mc){
    __syncthreads();   // previous chunk's compute done reading sS
    gl_lds16(Kp  + mc*4096 + t*8, sS + t*8);
    gl_lds16(Y0p + mc*4096 + t*8, sS + 4096  + t*8);
    gl_lds16(Y1p + mc*4096 + t*8, sS + 8192  + t*8);
    gl_lds16(Y2p + mc*4096 + t*8, sS + 12288 + t*8);
    __syncthreads();   // staged data visible (vmcnt drained by barrier)

    // ---- QK swapped: S^T chunk rows m = st*16+g*4+q, col = q-row lr ----
    f32x4 s[4];
#pragma unroll
    for (int st=0; st<4; ++st){
      const int ka = st*1024 + g*128 + lr*8;
      short8v k0 = *reinterpret_cast<const short8v*>(&sS[ka]);
      short8v k1 = *reinterpret_cast<const short8v*>(&sS[ka + 512]);
      f32x4 a = (f32x4){0.f,0.f,0.f,0.f};
      a = __builtin_amdgcn_mfma_f32_16x16x32_bf16(k0, qf0, a, 0,0,0);
      a = __builtin_amdgcn_mfma_f32_16x16x32_bf16(k1, qf1, a, 0,0,0);
      s[st] = a;
    }

    // ---- online softmax per q-row (state at each lane, rows indexed by lr) ----
    float cmax = -1e30f;
#pragma unroll
    for (int st=0; st<4; ++st)
#pragma unroll
      for (int q=0;q<4;q++) cmax = fmaxf(cmax, s[st][q]);
    cmax = fmaxf(cmax, __shfl_xor(cmax, 16));
    cmax = fmaxf(cmax, __shfl_xor(cmax, 32));
    float mnew = fmaxf(mrun, cmax);
    float alpha = __expf(mrun - mnew);
    mrun = mnew;

    float psum = 0.f;
#pragma unroll
    for (int st=0; st<4; ++st){
      union { ushort4 u; bf16 hh[4]; } pk;
#pragma unroll
      for (int q=0;q<4;q++){
        float p = __expf(s[st][q] - mrun);
        psum += p;
        pk.hh[q] = f2bf(p);
      }
      *reinterpret_cast<ushort4*>(&pw[lr*64 + ((st*16 + g*4) ^ pswz)]) = pk.u;
    }
    lsum = lsum*alpha + psum;

    float ar[4];
#pragma unroll
    for (int q=0;q<4;q++) ar[q] = __shfl(alpha, g*4+q);
#pragma unroll
    for (int y=0;y<3;y++)
#pragma unroll
      for (int dt=0;dt<4;dt++)
#pragma unroll
        for (int q=0;q<4;q++) U[y][dt][q] *= ar[q];

    // ---- PV x3 from LDS ----
#pragma unroll
    for (int ks=0; ks<2; ++ks){
      short8v a = *reinterpret_cast<const short8v*>(&pw[lr*64 + ((ks*32 + g*8) ^ pswz)]);
#pragma unroll
      for (int dt=0; dt<4; ++dt){
        const int ya = ks*2048 + ((dt*16+lr)<<5) + ((g ^ yswz)<<3);
        U[0][dt] = __builtin_amdgcn_mfma_f32_16x16x32_bf16(a, *reinterpret_cast<const short8v*>(&sS[4096  + ya]), U[0][dt], 0,0,0);
        U[1][dt] = __builtin_amdgcn_mfma_f32_16x16x32_bf16(a, *reinterpret_cast<const short8v*>(&sS[8192  + ya]), U[1][dt], 0,0,0);
        U[2][dt] = __builtin_amdgcn_mfma_f32_16x16x32_bf16(a, *reinterpret_cast<const short8v*>(&sS[12288 + ya]), U[2][dt], 0,0,0);
      }
    }
  }

  // ---- finalize: divide by row sums ----
  lsum += __shfl_xor(lsum, 16);
  lsum += __shfl_xor(lsum, 32);
  float linv = 1.f/lsum;
  float lq[4];
#pragma unroll
  for (int q=0;q<4;q++) lq[q] = __shfl(linv, g*4+q);
#pragma unroll
  for (int y=0;y<3;y++)
#pragma unroll
    for (int dt=0;dt<4;dt++)
#pragma unroll
      for (int q=0;q<4;q++) U[y][dt][q] *= lq[q];

  float sv[4];
#pragma unroll
  for (int dt=0;dt<4;dt++) sv[dt] = SV[bh*64 + dt*16 + lr];

  if (g == 3){
#pragma unroll
    for (int dt=0;dt<4;dt++) eU0[w][dt*16+lr] = U[0][dt][3];
  }
  if (g == 0){
#pragma unroll
    for (int dt=0;dt<4;dt++) eU2[w][dt*16+lr] = U[2][dt][0];
  }
  __syncthreads();

  // ---- combine O[r] = U0[r-1]+U1[r]+U2[r+1]+cb*SV into smOut (per-wave region) ----
  bf16* smOut = &pbuf[0][0];
#pragma unroll
  for (int dt=0; dt<4; ++dt){
    float u0s = __shfl(U[0][dt][3], (l - 16) & 63);
    if (g == 0) u0s = (w > 0) ? eU0[w-1][dt*16+lr] : 0.f;
    float u2s = __shfl(U[2][dt][0], (l + 16) & 63);
    if (g == 3) u2s = (w < 7) ? eU2[w+1][dt*16+lr] : 0.f;

    float base = cbv*sv[dt];
    float o0 = u0s         + U[1][dt][0] + U[2][dt][1] + base;
    float o1 = U[0][dt][0] + U[1][dt][1] + U[2][dt][2] + base;
    float o2 = U[0][dt][1] + U[1][dt][2] + U[2][dt][3] + base;
    float o3 = U[0][dt][2] + U[1][dt][3] + u2s         + base;

    const int d = dt*16 + lr;
    const int r0 = w*16 + g*4;
    smOut[(r0+0)*64 + d] = f2bf(o0);
    smOut[(r0+1)*64 + d] = f2bf(o1);
    smOut[(r0+2)*64 + d] = f2bf(o2);
    smOut[(r0+3)*64 + d] = f2bf(o3);

    const int ei = (bh*8 + tile)*64 + d;
    if (w == 0 && g == 0){
      E0[ei] = U[1][dt][0] + U[2][dt][1] + base;
      X1[ei] = U[2][dt][0];
    }
    if (w == 7 && g == 3){
      E127[ei] = U[0][dt][2] + U[1][dt][3] + base;
      X0[ei]   = U[0][dt][3];
    }
  }
  __syncthreads();

  // ---- coalesced copy-out: 4 threads per row, full 64B-line writes.
  // rows 0 and 127 written too; edge_patch overwrites them afterwards.
  {
    const int row = t >> 2, seg = t & 3;
    const bf16* src = smOut + row*64 + seg*16;
    uint4 v0 = *reinterpret_cast<const uint4*>(src);
    uint4 v1 = *reinterpret_cast<const uint4*>(src + 8);
    bf16* dst = midb + ((size_t)b*N_ + n0 + row)*C_ + h*D_ + seg*16;
    *reinterpret_cast<uint4*>(dst)     = v0;
    *reinterpret_cast<uint4*>(dst + 8) = v1;
  }
}

// ---- patch tile-edge rows: O[n0] = E0 + X0[prev], O[n0+127] = E127 + X1[next] ----
__global__ __launch_bounds__(256)
void edge_patch(const float* __restrict__ E0, const float* __restrict__ E127,
                const float* __restrict__ X0, const float* __restrict__ X1,
                bf16* __restrict__ midb)
{
  int idx = blockIdx.x*256 + threadIdx.x;   // 98304 total
  int d = idx & 63;
  int rs = (idx >> 6) & 1;
  int tile = (idx >> 7) & 7;
  int bh = idx >> 10;
  int b = bh / H_, h = bh - b*H_;
  int n0 = tile*128;
  float v; int n;
  if (rs == 0){
    v = E0[(bh*8+tile)*64 + d] + (tile > 0 ? X0[(bh*8+tile-1)*64 + d] : 0.f);
    n = n0;
  } else {
    v = E127[(bh*8+tile)*64 + d] + (tile < 7 ? X1[(bh*8+tile+1)*64 + d] : 0.f);
    n = n0 + 127;
  }
  midb[((size_t)b*N_ + n)*C_ + h*D_ + d] = f2bf(v);
}

extern "C" void kernel_launch(void* const* d_in, const int* in_sizes, int n_in,
                              void* d_out, int out_size, void* d_ws, size_t ws_size,
                              hipStream_t stream) {
  const float* x     = (const float*)d_in[0];
  const float* ctx   = (const float*)d_in[1];
  const float* Wq    = (const float*)d_in[2];
  const float* Wkv   = (const float*)d_in[3];
  const float* convw = (const float*)d_in[4];
  const float* convb = (const float*)d_in[5];
  const float* Wp    = (const float*)d_in[6];
  const float* bp    = (const float*)d_in[7];
  float* out = (float*)d_out;

  char* ws = (char*)d_ws;
  bf16* buf0 = (bf16*)(ws);                  // 12582912 (xb -> ctxb -> mid)
  bf16* Wqt  = (bf16*)(ws + 12582912);       // 1179648
  bf16* Wkvt = (bf16*)(ws + 13762560);       // 2359296
  bf16* Wpt  = (bf16*)(ws + 16121856);       // 1179648
  bf16* Qb   = (bf16*)(ws + 17301504);       // 12582912 (pre-scaled by 0.125)
  bf16* Kb   = (bf16*)(ws + 29884416);       // 12582912 (frag-tiled)
  bf16* Vt   = (bf16*)(ws + 42467328);       // 12582912 (V row-major -> Y2 tiled+swz)
  float* SVb = (float*)(ws + 55050240);      // 24576
  float* E0  = (float*)(ws + 55074816);      // 196608
  float* E127= (float*)(ws + 55271424);      // 196608
  float* X0  = (float*)(ws + 55468032);      // 196608
  float* X1  = (float*)(ws + 55664640);      // 196608 -> end 55861248

  // Y0/Y1 scratch in d_out (25.2 MB), fully overwritten by final GEMM
  bf16* Y0 = (bf16*)d_out;
  bf16* Y1 = (bf16*)((char*)d_out + 12582912);

  transpose_w<<<dim3(24,24), 256, 0, stream>>>(Wq,  Wqt,  768, 768);
  transpose_w<<<dim3(48,24), 256, 0, stream>>>(Wkv, Wkvt, 768, 1536);
  transpose_w<<<dim3(24,24), 256, 0, stream>>>(Wp,  Wpt,  768, 768);

  cvt_bf16<<<3072, 256, 0, stream>>>(x, buf0, 786432);
  gemm_bf16<<<384, 256, 0, stream>>>(buf0, Wqt, 768, 6, nullptr, nullptr, Qb, nullptr, nullptr, 0);
  cvt_bf16<<<3072, 256, 0, stream>>>(ctx, buf0, 786432);
  gemm_bf16<<<768, 256, 0, stream>>>(buf0, Wkvt, 768, 12, nullptr, nullptr, nullptr, Kb, Vt, 1);

  yprep<<<96, 1024, 0, stream>>>(Vt, Y0, Y1, SVb, convw);

  attn_coop<<<768, 512, 0, stream>>>(Qb, Kb, Y0, Y1, Vt, SVb, convb, buf0,
                                     E0, E127, X0, X1);
  edge_patch<<<384, 256, 0, stream>>>(E0, E127, X0, X1, buf0);

  gemm_bf16<<<384, 256, 0, stream>>>(buf0, Wpt, 768, 6, bp, out, nullptr, nullptr, nullptr, 2);
}

// Round 9
// 216.583 us; speedup vs baseline: 1.8703x; 1.0135x over previous
//
#include <hip/hip_runtime.h>
#include <hip/hip_bf16.h>

typedef __hip_bfloat16 bf16;
typedef __hip_bfloat162 bf162;

#define B_ 8
#define N_ 1024
#define M_ 1024
#define C_ 768
#define H_ 12
#define D_ 64

typedef __attribute__((ext_vector_type(8))) short short8v;
typedef __attribute__((ext_vector_type(4))) float f32x4;

__device__ __forceinline__ float bf2f(bf16 v){ return __bfloat162float(v); }
__device__ __forceinline__ bf16 f2bf(float v){ return __float2bfloat16(v); }

__device__ __forceinline__ void gl_lds16(const bf16* g, bf16* l){
  __builtin_amdgcn_global_load_lds((const __attribute__((address_space(1))) unsigned*)g,
                                   (__attribute__((address_space(3))) unsigned*)l, 16, 0, 0);
}

// ---------------- prep: fp32 -> bf16 convert (8 elems/thread) ----------------
__global__ __launch_bounds__(256)
void cvt_bf16(const float* __restrict__ in, bf16* __restrict__ out, int n8){
  int i = blockIdx.x*256 + threadIdx.x;
  if (i < n8){
    const float4* ip = reinterpret_cast<const float4*>(in) + 2*(size_t)i;
    float4 a = ip[0], b = ip[1];
    union { uint4 u; bf16 h[8]; } pk;
    pk.h[0]=f2bf(a.x); pk.h[1]=f2bf(a.y); pk.h[2]=f2bf(a.z); pk.h[3]=f2bf(a.w);
    pk.h[4]=f2bf(b.x); pk.h[5]=f2bf(b.y); pk.h[6]=f2bf(b.z); pk.h[7]=f2bf(b.w);
    reinterpret_cast<uint4*>(out)[i] = pk.u;
  }
}

// ---------------- prep: W[K][N] f32 -> Wt[N][K] bf16 ----------------
__global__ __launch_bounds__(256)
void transpose_w(const float* __restrict__ W, bf16* __restrict__ Wt, int K, int N){
  __shared__ float tile[32][33];
  const int n0 = blockIdx.x*32, k0 = blockIdx.y*32;
  const int tx = threadIdx.x & 31, ty = threadIdx.x >> 5;
#pragma unroll
  for (int i=0;i<32;i+=8) tile[ty+i][tx] = W[(size_t)(k0+ty+i)*N + n0+tx];
  __syncthreads();
#pragma unroll
  for (int i=0;i<32;i+=8) Wt[(size_t)(n0+ty+i)*K + k0+tx] = f2bf(tile[tx][ty+i]);
}

// ---- prep: per-(b,h) panel. Y_i tiled (m>>5)*2048 + d*32 + swizzled-m5.
// m-block (m5>>3) XORed with ((d>>1)&3). Y2 in place over Vt. Also SV.
__global__ __launch_bounds__(1024)
void yprep(bf16* __restrict__ Vt, bf16* __restrict__ Y0, bf16* __restrict__ Y1,
           float* __restrict__ SV, const float* __restrict__ conv_w)
{
  __shared__ bf16 sm[65536];
  const int t = threadIdx.x;
  const int bh = blockIdx.x;
  const int h = bh % H_;
  const size_t pbase = (size_t)bh * 65536;

  float w[9];
#pragma unroll
  for (int q=0;q<9;q++) w[q] = conv_w[h*9+q];

#pragma unroll
  for (int k=0;k<8;k++){
    int idx = k*8192 + t*8;
    *reinterpret_cast<uint4*>(&sm[idx]) = *reinterpret_cast<const uint4*>(Vt + pbase + idx);
  }
  __syncthreads();

  const int d = t >> 4;
  const int j = t & 15;
  const int xb = (d >> 1) & 3;
  float ssum = 0.f;
#pragma unroll
  for (int k=0;k<8;k++){
    const int moff = j*64 + k*8;
    const int base = d*1024 + moff;
    union { uint4 u; bf16 hh[8]; } mv;
    mv.u = *reinterpret_cast<const uint4*>(&sm[base]);
    float v[8];
#pragma unroll
    for (int e=0;e<8;e++) v[e] = bf2f(mv.hh[e]);
    float vl = (moff == 0)    ? 0.f : bf2f(sm[base-1]);
    float vr = (moff == 1016) ? 0.f : bf2f(sm[base+8]);

    union { uint4 u; bf16 hh[8]; } o0, o1, o2;
#pragma unroll
    for (int m=0;m<8;m++){
      float vm1 = (m==0) ? vl : v[m-1];
      float vp1 = (m==7) ? vr : v[m+1];
      o0.hh[m] = f2bf(w[0]*vp1 + w[1]*v[m] + w[2]*vm1);
      o1.hh[m] = f2bf(w[3]*vp1 + w[4]*v[m] + w[5]*vm1);
      o2.hh[m] = f2bf(w[6]*vp1 + w[7]*v[m] + w[8]*vm1);
      ssum += v[m];
    }
    const int blk = (moff >> 3) & 3;
    size_t go = pbase + ((size_t)(moff>>5)<<11) + d*32 + ((blk ^ xb)<<3);
    *reinterpret_cast<uint4*>(Y0 + go) = o0.u;
    *reinterpret_cast<uint4*>(Y1 + go) = o1.u;
    *reinterpret_cast<uint4*>(Vt + go) = o2.u;
  }

  ssum += __shfl_xor(ssum, 1);
  ssum += __shfl_xor(ssum, 2);
  ssum += __shfl_xor(ssum, 4);
  ssum += __shfl_xor(ssum, 8);
  if (j == 0) SV[bh*64 + d] = ssum;
}

// ---------------- bf16 MFMA GEMM: A[8192][K] @ Bt[N][K]^T ----------------
// mode 0: Qb pre-scaled by 0.125; mode 1: Kb frag-tiled / Vt; mode 2: +bias f32
__global__ __launch_bounds__(256)
void gemm_bf16(const bf16* __restrict__ A, const bf16* __restrict__ Bt, int K,
               int nbx, const float* __restrict__ bias,
               float* __restrict__ outf, bf16* __restrict__ outQ,
               bf16* __restrict__ outK, bf16* __restrict__ outV, int mode)
{
  __shared__ bf16 As[128*32];
  __shared__ bf16 Bs[128*32];

  const int nwg = 64*nbx, cpx = nwg >> 3;
  int bid = blockIdx.x;
  bid = (bid & 7)*cpx + (bid >> 3);
  const int rowb = bid / nbx, colb = bid - rowb*nbx;
  const int row0 = rowb*128, c0 = colb*128;

  const int t = threadIdx.x;
  const int w = t>>6, l = t&63, lr = l&15, g = l>>4;
  const int wr = w>>1, wc = w&1;

  const bf16* Ap = A + (size_t)row0*K;
  const bf16* Bp = Bt + (size_t)c0*K;
  const int srow = t>>2;
  const int schunk = (t&3)*8;

  f32x4 acc[4][4];
#pragma unroll
  for (int mi=0;mi<4;mi++)
#pragma unroll
    for (int ni=0;ni<4;ni++) acc[mi][ni] = (f32x4){0.f,0.f,0.f,0.f};

  for (int k0 = 0; k0 < K; k0 += 32){
    gl_lds16(Ap + (size_t)srow*K      + k0 + schunk, As + t*8);
    gl_lds16(Ap + (size_t)(srow+64)*K + k0 + schunk, As + 2048 + t*8);
    gl_lds16(Bp + (size_t)srow*K      + k0 + schunk, Bs + t*8);
    gl_lds16(Bp + (size_t)(srow+64)*K + k0 + schunk, Bs + 2048 + t*8);
    __syncthreads();

    short8v a[4], b[4];
#pragma unroll
    for (int mi=0;mi<4;mi++)
      a[mi] = *reinterpret_cast<const short8v*>(&As[(wr*64+mi*16+lr)*32 + g*8]);
#pragma unroll
    for (int ni=0;ni<4;ni++)
      b[ni] = *reinterpret_cast<const short8v*>(&Bs[(wc*64+ni*16+lr)*32 + g*8]);
#pragma unroll
    for (int mi=0;mi<4;mi++)
#pragma unroll
      for (int ni=0;ni<4;ni++)
        acc[mi][ni] = __builtin_amdgcn_mfma_f32_16x16x32_bf16(a[mi], b[ni], acc[mi][ni], 0,0,0);
    __syncthreads();
  }

  if (mode == 2){
    float bv[4];
#pragma unroll
    for (int ni=0;ni<4;ni++) bv[ni] = bias[c0 + wc*64 + ni*16 + lr];
#pragma unroll
    for (int mi=0;mi<4;mi++)
#pragma unroll
      for (int ni=0;ni<4;ni++){
        int c = c0 + wc*64 + ni*16 + lr;
#pragma unroll
        for (int q=0;q<4;q++){
          int grow = row0 + wr*64 + mi*16 + g*4 + q;
          outf[(size_t)grow*C_ + c] = acc[mi][ni][q] + bv[ni];
        }
      }
  } else if (mode == 0){
#pragma unroll
    for (int mi=0;mi<4;mi++)
#pragma unroll
      for (int ni=0;ni<4;ni++){
        int c = c0 + wc*64 + ni*16 + lr;
        int h = c >> 6, dd = c & 63;
#pragma unroll
        for (int q=0;q<4;q++){
          int grow = row0 + wr*64 + mi*16 + g*4 + q;
          int b = grow >> 10, n = grow & 1023;
          outQ[((((size_t)b*H_ + h)*N_ + n)<<6) + dd] = f2bf(acc[mi][ni][q] * 0.125f);
        }
      }
  } else {
#pragma unroll
    for (int mi=0;mi<4;mi++)
#pragma unroll
      for (int ni=0;ni<4;ni++){
        int c = c0 + wc*64 + ni*16 + lr;
        if (c < 768){
          int h = c >> 6, dd = c & 63;
#pragma unroll
          for (int q=0;q<4;q++){
            int grow = row0 + wr*64 + mi*16 + g*4 + q;
            int b = grow >> 10, m = grow & 1023;
            int eidx = ((m>>4)<<10) + ((dd>>3)<<7) + ((m&15)<<3) + (dd&7);
            outK[((size_t)b*H_ + h)*65536 + eidx] = f2bf(acc[mi][ni][q]);
          }
        } else {
          int cc = c - 768;
          int h = cc >> 6, dd = cc & 63;
          int grow = row0 + wr*64 + mi*16 + g*4;
          int b = grow >> 10, m = grow & 1023;
          union { ushort4 u; bf16 hh[4]; } pk;
#pragma unroll
          for (int q=0;q<4;q++) pk.hh[q] = f2bf(acc[mi][ni][q]);
          size_t off = (((size_t)b*H_ + h)*D_ + dd)*(size_t)M_ + m;
          *reinterpret_cast<ushort4*>(&outV[off]) = pk.u;
        }
      }
  }
}

// -------- cooperative flash attention, double-buffered staging w/ counted vmcnt
__global__ __launch_bounds__(512, 4)
void attn_coop(const bf16* __restrict__ Qb, const bf16* __restrict__ Kb,
               const bf16* __restrict__ Y0, const bf16* __restrict__ Y1,
               const bf16* __restrict__ Y2, const float* __restrict__ SV,
               const float* __restrict__ conv_b, bf16* __restrict__ midb,
               float* __restrict__ E0, float* __restrict__ E127,
               float* __restrict__ X0, float* __restrict__ X1)
{
  __shared__ bf16 sS[2][16384];     // 64 KB: double-buffered {K,Y0,Y1,Y2} chunks
  __shared__ bf16 pbuf[8][1024];    // 16 KB per-wave P [16 q][64 m], swizzled
  // post-loop aliases into sS (free after the final chunk barrier):
  float* eU0  = reinterpret_cast<float*>(&sS[0][0]);      // 2 KB
  float* eU2  = eU0 + 512;                                // 2 KB
  bf16*  smOut= reinterpret_cast<bf16*>(eU0 + 1024);      // 16 KB

  const int t = threadIdx.x, w = t>>6, l = t&63, lr = l&15, g = l>>4;
  int bid2 = (blockIdx.x & 7)*96 + (blockIdx.x >> 3);
  const int bh = bid2 >> 3, tile = bid2 & 7;
  const int b = bh / H_, h = bh - b*H_;
  const int n0 = tile*128;

  const bf16* Qp  = Qb + (size_t)bh*65536;
  const bf16* Kp  = Kb + (size_t)bh*65536;
  const bf16* Y0p = Y0 + (size_t)bh*65536;
  const bf16* Y1p = Y1 + (size_t)bh*65536;
  const bf16* Y2p = Y2 + (size_t)bh*65536;
  const float cbv = conv_b[h];

  const bf16* qp = Qp + (size_t)(n0 + w*16 + lr)*D_ + g*8;
  short8v qf0 = *reinterpret_cast<const short8v*>(qp);
  short8v qf1 = *reinterpret_cast<const short8v*>(qp + 32);

  float mrun = -INFINITY, lsum = 0.f;
  f32x4 U[3][4];
#pragma unroll
  for (int y=0;y<3;y++)
#pragma unroll
    for (int dt=0;dt<4;dt++) U[y][dt] = (f32x4){0.f,0.f,0.f,0.f};

  bf16* pw = pbuf[w];
  const int pswz = (lr & 7) << 3;
  const int yswz = (lr >> 1) & 3;

  // prologue: stage chunk 0 into buffer 0 (4 loads in flight)
  gl_lds16(Kp  + t*8, sS[0] + t*8);
  gl_lds16(Y0p + t*8, sS[0] + 4096  + t*8);
  gl_lds16(Y1p + t*8, sS[0] + 8192  + t*8);
  gl_lds16(Y2p + t*8, sS[0] + 12288 + t*8);

  for (int mc = 0; mc < 16; ++mc){
    const int cur = mc & 1;
    if (mc < 15){
      const size_t off = (size_t)(mc+1)*4096 + t*8;
      bf16* nb = sS[cur ^ 1];
      gl_lds16(Kp  + off, nb + t*8);
      gl_lds16(Y0p + off, nb + 4096  + t*8);
      gl_lds16(Y1p + off, nb + 8192  + t*8);
      gl_lds16(Y2p + off, nb + 12288 + t*8);
      asm volatile("s_waitcnt vmcnt(4)" ::: "memory");   // current chunk staged; next stays in flight
    } else {
      asm volatile("s_waitcnt vmcnt(0)" ::: "memory");
    }
    __builtin_amdgcn_s_barrier();                        // all waves' contributions visible
    const bf16* sb = sS[cur];

    // ---- QK swapped: S^T rows m = st*16+g*4+q, col = q-row lr ----
    f32x4 s[4];
    __builtin_amdgcn_s_setprio(1);
#pragma unroll
    for (int st=0; st<4; ++st){
      const int ka = st*1024 + g*128 + lr*8;
      short8v k0 = *reinterpret_cast<const short8v*>(&sb[ka]);
      short8v k1 = *reinterpret_cast<const short8v*>(&sb[ka + 512]);
      f32x4 a = (f32x4){0.f,0.f,0.f,0.f};
      a = __builtin_amdgcn_mfma_f32_16x16x32_bf16(k0, qf0, a, 0,0,0);
      a = __builtin_amdgcn_mfma_f32_16x16x32_bf16(k1, qf1, a, 0,0,0);
      s[st] = a;
    }
    __builtin_amdgcn_s_setprio(0);

    // ---- online softmax per q-row ----
    float cmax = -1e30f;
#pragma unroll
    for (int st=0; st<4; ++st)
#pragma unroll
      for (int q=0;q<4;q++) cmax = fmaxf(cmax, s[st][q]);
    cmax = fmaxf(cmax, __shfl_xor(cmax, 16));
    cmax = fmaxf(cmax, __shfl_xor(cmax, 32));
    const bool anyGrow = __any(cmax > mrun);
    float mnew = fmaxf(mrun, cmax);
    float alpha = __expf(mrun - mnew);
    mrun = mnew;

    float psum = 0.f;
#pragma unroll
    for (int st=0; st<4; ++st){
      union { ushort4 u; bf16 hh[4]; } pk;
#pragma unroll
      for (int q=0;q<4;q++){
        float p = __expf(s[st][q] - mrun);
        psum += p;
        pk.hh[q] = f2bf(p);
      }
      *reinterpret_cast<ushort4*>(&pw[lr*64 + ((st*16 + g*4) ^ pswz)]) = pk.u;
    }

    if (anyGrow){   // T13: skip O(48)-FMA rescale when no row's max grew
      lsum = lsum*alpha + psum;
      float ar[4];
#pragma unroll
      for (int q=0;q<4;q++) ar[q] = __shfl(alpha, g*4+q);
#pragma unroll
      for (int y=0;y<3;y++)
#pragma unroll
        for (int dt=0;dt<4;dt++)
#pragma unroll
          for (int q=0;q<4;q++) U[y][dt][q] *= ar[q];
    } else {
      lsum += psum;
    }

    // ---- PV x3 from LDS ----
    __builtin_amdgcn_s_setprio(1);
#pragma unroll
    for (int ks=0; ks<2; ++ks){
      short8v a = *reinterpret_cast<const short8v*>(&pw[lr*64 + ((ks*32 + g*8) ^ pswz)]);
#pragma unroll
      for (int dt=0; dt<4; ++dt){
        const int ya = ks*2048 + ((dt*16+lr)<<5) + ((g ^ yswz)<<3);
        U[0][dt] = __builtin_amdgcn_mfma_f32_16x16x32_bf16(a, *reinterpret_cast<const short8v*>(&sb[4096  + ya]), U[0][dt], 0,0,0);
        U[1][dt] = __builtin_amdgcn_mfma_f32_16x16x32_bf16(a, *reinterpret_cast<const short8v*>(&sb[8192  + ya]), U[1][dt], 0,0,0);
        U[2][dt] = __builtin_amdgcn_mfma_f32_16x16x32_bf16(a, *reinterpret_cast<const short8v*>(&sb[12288 + ya]), U[2][dt], 0,0,0);
      }
    }
    __builtin_amdgcn_s_setprio(0);
    __builtin_amdgcn_s_barrier();   // all waves done reading sb before it is restaged
  }

  // ---- finalize ----
  lsum += __shfl_xor(lsum, 16);
  lsum += __shfl_xor(lsum, 32);
  float linv = 1.f/lsum;
  float lq[4];
#pragma unroll
  for (int q=0;q<4;q++) lq[q] = __shfl(linv, g*4+q);
#pragma unroll
  for (int y=0;y<3;y++)
#pragma unroll
    for (int dt=0;dt<4;dt++)
#pragma unroll
      for (int q=0;q<4;q++) U[y][dt][q] *= lq[q];

  float sv[4];
#pragma unroll
  for (int dt=0;dt<4;dt++) sv[dt] = SV[bh*64 + dt*16 + lr];

  if (g == 3){
#pragma unroll
    for (int dt=0;dt<4;dt++) eU0[w*64 + dt*16+lr] = U[0][dt][3];
  }
  if (g == 0){
#pragma unroll
    for (int dt=0;dt<4;dt++) eU2[w*64 + dt*16+lr] = U[2][dt][0];
  }
  __syncthreads();

  // ---- combine O[r] = U0[r-1]+U1[r]+U2[r+1]+cb*SV into smOut ----
#pragma unroll
  for (int dt=0; dt<4; ++dt){
    float u0s = __shfl(U[0][dt][3], (l - 16) & 63);
    if (g == 0) u0s = (w > 0) ? eU0[(w-1)*64 + dt*16+lr] : 0.f;
    float u2s = __shfl(U[2][dt][0], (l + 16) & 63);
    if (g == 3) u2s = (w < 7) ? eU2[(w+1)*64 + dt*16+lr] : 0.f;

    float base = cbv*sv[dt];
    float o0 = u0s         + U[1][dt][0] + U[2][dt][1] + base;
    float o1 = U[0][dt][0] + U[1][dt][1] + U[2][dt][2] + base;
    float o2 = U[0][dt][1] + U[1][dt][2] + U[2][dt][3] + base;
    float o3 = U[0][dt][2] + U[1][dt][3] + u2s         + base;

    const int d = dt*16 + lr;
    const int r0 = w*16 + g*4;
    smOut[(r0+0)*64 + d] = f2bf(o0);
    smOut[(r0+1)*64 + d] = f2bf(o1);
    smOut[(r0+2)*64 + d] = f2bf(o2);
    smOut[(r0+3)*64 + d] = f2bf(o3);

    const int ei = (bh*8 + tile)*64 + d;
    if (w == 0 && g == 0){
      E0[ei] = U[1][dt][0] + U[2][dt][1] + base;
      X1[ei] = U[2][dt][0];
    }
    if (w == 7 && g == 3){
      E127[ei] = U[0][dt][2] + U[1][dt][3] + base;
      X0[ei]   = U[0][dt][3];
    }
  }
  __syncthreads();

  // ---- coalesced copy-out (rows 0/127 later overwritten by edge_patch) ----
  {
    const int row = t >> 2, seg = t & 3;
    const bf16* src = smOut + row*64 + seg*16;
    uint4 v0 = *reinterpret_cast<const uint4*>(src);
    uint4 v1 = *reinterpret_cast<const uint4*>(src + 8);
    bf16* dst = midb + ((size_t)b*N_ + n0 + row)*C_ + h*D_ + seg*16;
    *reinterpret_cast<uint4*>(dst)     = v0;
    *reinterpret_cast<uint4*>(dst + 8) = v1;
  }
}

// ---- patch tile-edge rows ----
__global__ __launch_bounds__(256)
void edge_patch(const float* __restrict__ E0, const float* __restrict__ E127,
                const float* __restrict__ X0, const float* __restrict__ X1,
                bf16* __restrict__ midb)
{
  int idx = blockIdx.x*256 + threadIdx.x;
  int d = idx & 63;
  int rs = (idx >> 6) & 1;
  int tile = (idx >> 7) & 7;
  int bh = idx >> 10;
  int b = bh / H_, h = bh - b*H_;
  int n0 = tile*128;
  float v; int n;
  if (rs == 0){
    v = E0[(bh*8+tile)*64 + d] + (tile > 0 ? X0[(bh*8+tile-1)*64 + d] : 0.f);
    n = n0;
  } else {
    v = E127[(bh*8+tile)*64 + d] + (tile < 7 ? X1[(bh*8+tile+1)*64 + d] : 0.f);
    n = n0 + 127;
  }
  midb[((size_t)b*N_ + n)*C_ + h*D_ + d] = f2bf(v);
}

extern "C" void kernel_launch(void* const* d_in, const int* in_sizes, int n_in,
                              void* d_out, int out_size, void* d_ws, size_t ws_size,
                              hipStream_t stream) {
  const float* x     = (const float*)d_in[0];
  const float* ctx   = (const float*)d_in[1];
  const float* Wq    = (const float*)d_in[2];
  const float* Wkv   = (const float*)d_in[3];
  const float* convw = (const float*)d_in[4];
  const float* convb = (const float*)d_in[5];
  const float* Wp    = (const float*)d_in[6];
  const float* bp    = (const float*)d_in[7];
  float* out = (float*)d_out;

  char* ws = (char*)d_ws;
  bf16* buf0 = (bf16*)(ws);                  // 12582912 (xb -> ctxb -> mid)
  bf16* Wqt  = (bf16*)(ws + 12582912);
  bf16* Wkvt = (bf16*)(ws + 13762560);
  bf16* Wpt  = (bf16*)(ws + 16121856);
  bf16* Qb   = (bf16*)(ws + 17301504);       // pre-scaled by 0.125
  bf16* Kb   = (bf16*)(ws + 29884416);       // frag-tiled
  bf16* Vt   = (bf16*)(ws + 42467328);       // V row-major -> Y2 tiled+swz
  float* SVb = (float*)(ws + 55050240);
  float* E0  = (float*)(ws + 55074816);
  float* E127= (float*)(ws + 55271424);
  float* X0  = (float*)(ws + 55468032);
  float* X1  = (float*)(ws + 55664640);      // -> end 55861248

  bf16* Y0 = (bf16*)d_out;
  bf16* Y1 = (bf16*)((char*)d_out + 12582912);

  transpose_w<<<dim3(24,24), 256, 0, stream>>>(Wq,  Wqt,  768, 768);
  transpose_w<<<dim3(48,24), 256, 0, stream>>>(Wkv, Wkvt, 768, 1536);
  transpose_w<<<dim3(24,24), 256, 0, stream>>>(Wp,  Wpt,  768, 768);

  cvt_bf16<<<3072, 256, 0, stream>>>(x, buf0, 786432);
  gemm_bf16<<<384, 256, 0, stream>>>(buf0, Wqt, 768, 6, nullptr, nullptr, Qb, nullptr, nullptr, 0);
  cvt_bf16<<<3072, 256, 0, stream>>>(ctx, buf0, 786432);
  gemm_bf16<<<768, 256, 0, stream>>>(buf0, Wkvt, 768, 12, nullptr, nullptr, nullptr, Kb, Vt, 1);

  yprep<<<96, 1024, 0, stream>>>(Vt, Y0, Y1, SVb, convw);

  attn_coop<<<768, 512, 0, stream>>>(Qb, Kb, Y0, Y1, Vt, SVb, convb, buf0,
                                     E0, E127, X0, X1);
  edge_patch<<<384, 256, 0, stream>>>(E0, E127, X0, X1, buf0);

  gemm_bf16<<<384, 256, 0, stream>>>(buf0, Wpt, 768, 6, bp, out, nullptr, nullptr, nullptr, 2);
}